// Round 1
// baseline (1224.725 us; speedup 1.0000x reference)
//
#include <hip/hip_runtime.h>
#include <hip/hip_bf16.h>

// Elman RNN on MI355X: h_t = tanh([h_{t-1} | x_t] @ [Wh|Wi]^T + (Wh_b+Wi_b)); out = h_T @ Wo^T + Wo_b
// T=128, B=512, E=256, H=1024, O=256.

#define T_ 128
#define B_ 512
#define E_ 256
#define H_ 1024
#define O_ 256
#define KC_ (H_ + E_)   // 1280

typedef __bf16 bf16x8 __attribute__((ext_vector_type(8)));
typedef float  f32x4  __attribute__((ext_vector_type(4)));

__device__ __forceinline__ unsigned short f2bf(float f) {
  unsigned u = __float_as_uint(f);
  u += 0x7fff + ((u >> 16) & 1);   // round-to-nearest-even
  return (unsigned short)(u >> 16);
}

// ---------------------------------------------------------------------------
// prep: pack [Wh | Wi] -> bf16 Wcat[1024][1280], Wo -> bf16, bias = Wh_b+Wi_b,
// h0 = zeros (ws is poisoned 0xAA, so we must zero it every launch).
// ---------------------------------------------------------------------------
__global__ void prep_kernel(const float* __restrict__ Wh_w, const float* __restrict__ Wh_b,
                            const float* __restrict__ Wi_w, const float* __restrict__ Wi_b,
                            const float* __restrict__ Wo_w,
                            unsigned short* __restrict__ Wcat,
                            unsigned short* __restrict__ Wo_bf,
                            float* __restrict__ bias,
                            unsigned short* __restrict__ h0) {
  int idx = blockIdx.x * blockDim.x + threadIdx.x;
  int stride = gridDim.x * blockDim.x;
  for (int i = idx; i < H_ * KC_; i += stride) {
    int j = i / KC_, k = i - j * KC_;
    float v = (k < H_) ? Wh_w[j * H_ + k] : Wi_w[j * E_ + (k - H_)];
    Wcat[i] = f2bf(v);
  }
  for (int i = idx; i < O_ * H_; i += stride) Wo_bf[i] = f2bf(Wo_w[i]);
  for (int i = idx; i < H_; i += stride) bias[i] = Wh_b[i] + Wi_b[i];
  for (int i = idx; i < B_ * H_; i += stride) h0[i] = 0;  // bf16 +0.0
}

// ---------------------------------------------------------------------------
// 32x64-tile bf16 GEMM with B^T weights, fused bias (+tanh) epilogue.
//   D[m][n] = act( sum_k A[m,k] * W[n,k] + bias[n] )
// A part-1 is bf16 (lda elems); k-blocks >= H_/64 come from fp32 X (512x256),
// converted at stage time (HASX). LDS tiles XOR-swizzled (chunk ^= row&7) so
// ds_read_b128 column reads are ~2-way (free) instead of 16-way.
// 4 waves: wave tile 16(m) x 32(n), 2x f32x4 accumulators.
// ---------------------------------------------------------------------------
template <int KT, bool HASX, bool TANH, bool OUTBF>
__global__ __launch_bounds__(256) void gemm32x64(
    const unsigned short* __restrict__ A, int lda,
    const float* __restrict__ X,
    const unsigned short* __restrict__ W, int ldw,
    const float* __restrict__ bias,
    void* __restrict__ outp, int ldo) {
  __shared__ __align__(16) unsigned char As[32 * 128];  // 32 rows x 64 bf16
  __shared__ __align__(16) unsigned char Bs[64 * 128];  // 64 rows x 64 bf16

  const int tid  = threadIdx.x;
  const int lane = tid & 63;
  const int wave = tid >> 6;
  const int bm = blockIdx.x, bn = blockIdx.y;
  const int wm = (wave >> 1) * 16;  // 0/16
  const int wn = (wave & 1) * 32;   // 0/32

  f32x4 acc0 = {0.f, 0.f, 0.f, 0.f};
  f32x4 acc1 = {0.f, 0.f, 0.f, 0.f};

  for (int kt = 0; kt < KT; ++kt) {
    // ---- stage A tile (32x64): 256 chunks of 16B, 1 per thread
    {
      int row = tid >> 3, c8 = tid & 7;
      int gb = bm * 32 + row;
      uint4 v;
      if (!HASX || kt < (H_ / 64)) {
        v = *reinterpret_cast<const uint4*>(A + gb * lda + kt * 64 + c8 * 8);
      } else {
        const float* p = X + gb * E_ + (kt - H_ / 64) * 64 + c8 * 8;
        float4 f0 = reinterpret_cast<const float4*>(p)[0];
        float4 f1 = reinterpret_cast<const float4*>(p)[1];
        v.x = (unsigned)f2bf(f0.x) | ((unsigned)f2bf(f0.y) << 16);
        v.y = (unsigned)f2bf(f0.z) | ((unsigned)f2bf(f0.w) << 16);
        v.z = (unsigned)f2bf(f1.x) | ((unsigned)f2bf(f1.y) << 16);
        v.w = (unsigned)f2bf(f1.z) | ((unsigned)f2bf(f1.w) << 16);
      }
      *reinterpret_cast<uint4*>(As + row * 128 + ((c8 ^ (row & 7)) << 4)) = v;
    }
    // ---- stage B tile (64x64): 512 chunks, 2 per thread
#pragma unroll
    for (int p2 = 0; p2 < 2; ++p2) {
      int id = p2 * 256 + tid;
      int row = id >> 3, c8 = id & 7;
      int gn = bn * 64 + row;
      uint4 v = *reinterpret_cast<const uint4*>(W + gn * ldw + kt * 64 + c8 * 8);
      *reinterpret_cast<uint4*>(Bs + row * 128 + ((c8 ^ (row & 7)) << 4)) = v;
    }
    __syncthreads();
    // ---- compute: 2 K-steps of 32, 16x16x32 MFMA
#pragma unroll
    for (int ks = 0; ks < 2; ++ks) {
      int koff = ks * 4 + (lane >> 4);
      int am = wm + (lane & 15);
      bf16x8 a = *reinterpret_cast<const bf16x8*>(As + am * 128 + ((koff ^ (am & 7)) << 4));
      int n0 = wn + (lane & 15);
      int n1 = n0 + 16;
      bf16x8 b0 = *reinterpret_cast<const bf16x8*>(Bs + n0 * 128 + ((koff ^ (n0 & 7)) << 4));
      bf16x8 b1 = *reinterpret_cast<const bf16x8*>(Bs + n1 * 128 + ((koff ^ (n1 & 7)) << 4));
      acc0 = __builtin_amdgcn_mfma_f32_16x16x32_bf16(a, b0, acc0, 0, 0, 0);
      acc1 = __builtin_amdgcn_mfma_f32_16x16x32_bf16(a, b1, acc1, 0, 0, 0);
    }
    __syncthreads();
  }

  // ---- epilogue: C/D layout col=lane&15, row=(lane>>4)*4+reg (guide §3, m89/m91)
  const int col = lane & 15;
  const int gr0 = bm * 32 + wm + ((lane >> 4) << 2);
#pragma unroll
  for (int ni = 0; ni < 2; ++ni) {
    f32x4 acc = ni ? acc1 : acc0;
    int gc = bn * 64 + wn + ni * 16 + col;
    float bv = bias[gc];
#pragma unroll
    for (int r = 0; r < 4; ++r) {
      float v = acc[r] + bv;
      if (TANH) v = tanhf(v);
      if (OUTBF)
        reinterpret_cast<unsigned short*>(outp)[(gr0 + r) * ldo + gc] = f2bf(v);
      else
        reinterpret_cast<float*>(outp)[(gr0 + r) * ldo + gc] = v;
    }
  }
}

// ---------------------------------------------------------------------------
extern "C" void kernel_launch(void* const* d_in, const int* in_sizes, int n_in,
                              void* d_out, int out_size, void* d_ws, size_t ws_size,
                              hipStream_t stream) {
  const float* seq  = (const float*)d_in[0];
  const float* Wh_w = (const float*)d_in[1];
  const float* Wh_b = (const float*)d_in[2];
  const float* Wi_w = (const float*)d_in[3];
  const float* Wi_b = (const float*)d_in[4];
  const float* Wo_w = (const float*)d_in[5];
  const float* Wo_b = (const float*)d_in[6];

  char* ws = (char*)d_ws;
  unsigned short* Wcat  = (unsigned short*)ws; ws += (size_t)H_ * KC_ * 2;  // 2.62 MB
  unsigned short* Wo_bf = (unsigned short*)ws; ws += (size_t)O_ * H_ * 2;   // 0.52 MB
  float*          bias  = (float*)ws;          ws += (size_t)H_ * 4;        // 4 KB
  unsigned short* h0    = (unsigned short*)ws; ws += (size_t)B_ * H_ * 2;   // 1 MB
  unsigned short* h1    = (unsigned short*)ws;                              // 1 MB

  prep_kernel<<<1024, 256, 0, stream>>>(Wh_w, Wh_b, Wi_w, Wi_b, Wo_w,
                                        Wcat, Wo_bf, bias, h0);

  unsigned short* hc = h0;
  unsigned short* hn = h1;
  for (int t = 0; t < T_; ++t) {
    gemm32x64<KC_ / 64, true, true, true><<<dim3(B_ / 32, H_ / 64), 256, 0, stream>>>(
        hc, H_, seq + (size_t)t * B_ * E_, Wcat, KC_, bias, hn, H_);
    unsigned short* tmp = hc; hc = hn; hn = tmp;
  }
  // final: out = h_T @ Wo^T + Wo_b  (fp32 out)
  gemm32x64<H_ / 64, false, false, false><<<dim3(B_ / 32, O_ / 64), 256, 0, stream>>>(
      hc, H_, nullptr, Wo_bf, H_, Wo_b, d_out, O_);
}